// Round 14
// baseline (644.321 us; speedup 1.0000x reference)
//
#include <hip/hip_runtime.h>
#include <hip/hip_fp16.h>
#include <cstdint>

#define N_NODES 50000
#define N_EDGES 600000
#define HDIM    128
#define NGRAPH  256
#define EPSBN   1e-5f
#define NEG     0.2f
#define SCAN_B  196   // ceil(50000/256)

__device__ __forceinline__ float lrelu(float v){ return v > 0.f ? v : NEG*v; }

typedef _Float16     f16x8 __attribute__((ext_vector_type(8)));
typedef float        f32x4 __attribute__((ext_vector_type(4)));
typedef unsigned int u32x4 __attribute__((ext_vector_type(4)));

// ============ prep: weight swizzle to MFMA-fragment order + degree + bounds ===
__global__ void prep_kernel(const float* __restrict__ W1, const float* __restrict__ Wg,
                            const float* __restrict__ W3, __half* __restrict__ Wt1,
                            __half* __restrict__ Wtg, __half* __restrict__ Wt3,
                            const int* __restrict__ ei, int* __restrict__ degi,
                            const int* __restrict__ batch, int* __restrict__ start){
  int b = blockIdx.x;
  if (b < 192){
    const float* W = (b < 64) ? W1 : (b < 128 ? Wg : W3);
    __half*     Wt = (b < 64) ? Wt1 : (b < 128 ? Wtg : Wt3);
    int idx = (b & 63)*256 + threadIdx.x;     // 0..16383
    int k = idx >> 7, n = idx & 127;
    int kc = k >> 5, q = (k >> 3) & 3, j = k & 7;
    int nt = n >> 4, c16 = n & 15;
    Wt[(((kc*8 + nt)*4 + q)*16 + c16)*8 + j] = __float2half(W[idx]);
  } else if (b < 192 + 2344){
    int e = (b - 192)*256 + threadIdx.x;
    if (e < N_EDGES) atomicAdd(&degi[ei[N_EDGES + e]], 1);
  } else {
    int i = (b - 192 - 2344)*256 + threadIdx.x;
    if (i >= N_NODES) return;
    int bb = batch[i];
    int p = (i == 0) ? -1 : batch[i-1];
    for (int g = p+1; g <= bb; ++g) start[g] = i;
    if (i == N_NODES-1)
      for (int g = bb+1; g <= NGRAPH; ++g) start[g] = N_NODES;
  }
}

// ============ CSR offsets (block scan + atomic ticket) + degree histogram =====
__global__ void scan_kernel(const int* __restrict__ degi, int2* __restrict__ seg,
                            int* __restrict__ work, float* __restrict__ dis,
                            int* __restrict__ gctr, int* __restrict__ hist){
  __shared__ int sm[256];
  __shared__ int base;
  int t = threadIdx.x; int i = blockIdx.x*256 + t;
  int v = (i < N_NODES) ? degi[i] : 0;
  if (i < N_NODES){
    dis[i] = rsqrtf((float)v + 1.f);   // +1 = self loop
    atomicAdd(&hist[min(v, 63)], 1);   // degree histogram for counting sort
  }
  sm[t] = v; __syncthreads();
  for (int off = 1; off < 256; off <<= 1){
    int add = (t >= off) ? sm[t - off] : 0;
    __syncthreads();
    sm[t] += add; __syncthreads();
  }
  if (t == 255) base = atomicAdd(gctr, sm[255]);
  __syncthreads();
  if (i < N_NODES){
    int r = base + sm[t] - v;    // exclusive prefix within block + global base
    seg[i] = make_int2(r, v);
    work[i] = r;
  }
}
// 64-bucket exclusive prefix (1 wave) -> hist becomes scatter cursors
__global__ void hist_prefix(int* __restrict__ hist){
  int t = threadIdx.x;                 // 64 threads
  int v = hist[t];
  int p = v;
  for (int off = 1; off < 64; off <<= 1){
    int u = __shfl_up(p, off);
    if (t >= off) p += u;
  }
  hist[t] = p - v;                     // exclusive
}
// edges -> colx  |  nodes -> degree-sorted order
__global__ void csr_scatter(const int* __restrict__ ei, int* __restrict__ work,
                            int* __restrict__ colx, const int2* __restrict__ seg,
                            int* __restrict__ hist, int* __restrict__ order){
  int b = blockIdx.x;
  if (b < 2344){
    int e = b*256 + threadIdx.x;
    if (e >= N_EDGES) return;
    int s = ei[e], d = ei[N_EDGES + e];
    int pos = atomicAdd(&work[d], 1);
    colx[pos] = s;
  } else {
    int i = (b - 2344)*256 + threadIdx.x;
    if (i >= N_NODES) return;
    int d = min(seg[i].y, 63);
    int pos = atomicAdd(&hist[d], 1);
    order[pos] = i;
  }
}

// ============ MFMA GEMM: Y = act(X) @ W, fp16 out ============
template<bool BN, bool F32IN, bool ATT, bool SCALE>
__global__ __launch_bounds__(256) void gemm_mfma(const void* __restrict__ Xv,
    const __half* __restrict__ Wt,
    const float* __restrict__ S, const float* __restrict__ Q,
    const float* __restrict__ gam, const float* __restrict__ bet,
    __half* __restrict__ Yh,
    const float* __restrict__ asr, const float* __restrict__ adt,
    float* __restrict__ al_s, float* __restrict__ al_d,
    const float* __restrict__ dis){
  __shared__ _Float16 scl[128], shl[128];
  const int t    = threadIdx.x;
  if (BN){
    if (t < 128){
      float mean = S[t] * (1.f/(float)N_NODES);
      float var  = fmaxf(Q[t]*(1.f/(float)N_NODES) - mean*mean, 0.f);
      float scale = gam[t]*rsqrtf(var + EPSBN);
      float shift = bet[t] - mean*scale;
      scl[t] = (_Float16)scale;
      shl[t] = (_Float16)shift;
    }
    __syncthreads();
  }
  const int wave = t >> 6, lane = t & 63;
  const int q    = lane >> 4, c16 = lane & 15;
  const int m0   = blockIdx.x*64 + wave*16;
  const int row  = m0 + c16;
  const int arow = (row > N_NODES-1) ? N_NODES-1 : row;   // tail clamp (reads only)

  f32x4 acc[8];
#pragma unroll
  for (int i = 0; i < 8; ++i) acc[i] = (f32x4){0.f,0.f,0.f,0.f};

  const f16x8* Wt8 = (const f16x8*)Wt;

#pragma unroll
  for (int kc = 0; kc < 4; ++kc){
    const int kof = kc*32 + q*8;
    f16x8 a;
    if (F32IN){
      const float* xp = (const float*)Xv + (long)arow*128 + kof;
      float4 x0 = *(const float4*)xp;
      float4 x1 = *(const float4*)(xp + 4);
      a[0]=(_Float16)x0.x; a[1]=(_Float16)x0.y; a[2]=(_Float16)x0.z; a[3]=(_Float16)x0.w;
      a[4]=(_Float16)x1.x; a[5]=(_Float16)x1.y; a[6]=(_Float16)x1.z; a[7]=(_Float16)x1.w;
    } else {
      f16x8 raw = *(const f16x8*)((const _Float16*)Xv + (long)arow*128 + kof);
      if (BN){
        f16x8 scv = *(const f16x8*)(scl + kof);
        f16x8 shv = *(const f16x8*)(shl + kof);
#pragma unroll
        for (int i = 0; i < 8; ++i){
          _Float16 v = (_Float16)(raw[i]*scv[i] + shv[i]);
          a[i] = v > (_Float16)0 ? v : (_Float16)0;
        }
      } else {
        a = raw;
      }
    }
#pragma unroll
    for (int nt = 0; nt < 8; ++nt){
      f16x8 b = Wt8[(kc*8 + nt)*64 + lane];   // lane-contiguous fragment
      acc[nt] = __builtin_amdgcn_mfma_f32_16x16x32_f16(b, a, acc[nt], 0, 0, 0);
    }
  }
  float rs = SCALE ? dis[arow] : 1.f;
  if (row < N_NODES){
    __half* yp = Yh + (long)row*128 + q*4;
#pragma unroll
    for (int nt = 0; nt < 8; ++nt){
      union { uint2 u; __half2 h[2]; } pk;
      pk.h[0] = __floats2half2_rn(acc[nt][0]*rs, acc[nt][1]*rs);
      pk.h[1] = __floats2half2_rn(acc[nt][2]*rs, acc[nt][3]*rs);
      *(uint2*)(yp + nt*16) = pk.u;
    }
  }
  if (ATT){
    float s = 0.f, d = 0.f;
#pragma unroll
    for (int nt = 0; nt < 8; ++nt){
      float4 av = *(const float4*)(asr + nt*16 + q*4);
      float4 bv = *(const float4*)(adt + nt*16 + q*4);
      s += acc[nt][0]*av.x + acc[nt][1]*av.y + acc[nt][2]*av.z + acc[nt][3]*av.w;
      d += acc[nt][0]*bv.x + acc[nt][1]*bv.y + acc[nt][2]*bv.z + acc[nt][3]*bv.w;
    }
    s += __shfl_xor(s, 16); s += __shfl_xor(s, 32);
    d += __shfl_xor(d, 16); d += __shfl_xor(d, 32);
    if (q == 0 && row < N_NODES){ al_s[row] = s; al_d[row] = d; }
  }
}

// ============ GCN aggregation: 1 group = 1 node, degree-sorted order ==========
__global__ __launch_bounds__(256) void gcn_agg(const _Float16* __restrict__ Ah,
    const float* __restrict__ dis, const int2* __restrict__ seg,
    const int* __restrict__ colx, const int* __restrict__ order,
    __half* __restrict__ Bh){
  const int t = threadIdx.x;
  const int grp = t >> 4, p = t & 15;
  const int n = order[blockIdx.x*16 + grp];   // degree-sorted: balanced block
  const int2 sg = seg[n];
  const int e0 = sg.x, cnt = sg.y;
  f16x8 self = *(const f16x8*)(Ah + (long)n*128 + p*8);
  float acc[8];
#pragma unroll
  for (int i = 0; i < 8; ++i) acc[i] = (float)self[i];
  int j = 0;
  for (; j + 1 < cnt; j += 2){
    int s0 = colx[e0 + j];
    int s1 = colx[e0 + j + 1];
    f16x8 r0 = *(const f16x8*)(Ah + (long)s0*128 + p*8);
    f16x8 r1 = *(const f16x8*)(Ah + (long)s1*128 + p*8);
#pragma unroll
    for (int i = 0; i < 8; ++i) acc[i] += (float)r0[i] + (float)r1[i];
  }
  if (j < cnt){
    int s0 = colx[e0 + j];
    f16x8 r0 = *(const f16x8*)(Ah + (long)s0*128 + p*8);
#pragma unroll
    for (int i = 0; i < 8; ++i) acc[i] += (float)r0[i];
  }
  float dn = dis[n];
  union { u32x4 u; __half2 h[4]; } pk;
#pragma unroll
  for (int i = 0; i < 4; ++i)
    pk.h[i] = __floats2half2_rn(acc[2*i]*dn, acc[2*i+1]*dn);
  __builtin_nontemporal_store(pk.u, (u32x4*)(Bh + (long)n*128 + p*8));
}

// ============ GAT aggregation: 1 group = 1 node, online softmax, sorted =======
__global__ __launch_bounds__(256) void gat_agg(const _Float16* __restrict__ Ah,
    const float* __restrict__ al_s, const float* __restrict__ al_d,
    const int2* __restrict__ seg, const int* __restrict__ colx,
    const int* __restrict__ order, __half* __restrict__ Bh){
  const int t = threadIdx.x;
  const int grp = t >> 4, p = t & 15;
  const int n = order[blockIdx.x*16 + grp];
  const int2 sg = seg[n];
  const int e0 = sg.x, cnt = sg.y;
  const float adn = al_d[n];
  float m = lrelu(al_s[n] + adn);     // self seeds the running max
  float denom = 1.f;                  // self weight exp(0)
  f16x8 self = *(const f16x8*)(Ah + (long)n*128 + p*8);
  float acc[8];
#pragma unroll
  for (int i = 0; i < 8; ++i) acc[i] = (float)self[i];
  int j = 0;
  for (; j + 1 < cnt; j += 2){
    int s0 = colx[e0 + j];
    int s1 = colx[e0 + j + 1];
    float a0 = lrelu(al_s[s0] + adn);
    float a1 = lrelu(al_s[s1] + adn);
    f16x8 r0 = *(const f16x8*)(Ah + (long)s0*128 + p*8);
    f16x8 r1 = *(const f16x8*)(Ah + (long)s1*128 + p*8);
    float nm = fmaxf(m, fmaxf(a0, a1));
    float sc = __expf(m - nm);
    float w0 = __expf(a0 - nm);
    float w1 = __expf(a1 - nm);
    denom = denom*sc + w0 + w1;
    m = nm;
#pragma unroll
    for (int i = 0; i < 8; ++i)
      acc[i] = acc[i]*sc + w0*(float)r0[i] + w1*(float)r1[i];
  }
  if (j < cnt){
    int s0 = colx[e0 + j];
    float a0 = lrelu(al_s[s0] + adn);
    f16x8 r0 = *(const f16x8*)(Ah + (long)s0*128 + p*8);
    float nm = fmaxf(m, a0);
    float sc = __expf(m - nm);
    float w0 = __expf(a0 - nm);
    denom = denom*sc + w0;
#pragma unroll
    for (int i = 0; i < 8; ++i) acc[i] = acc[i]*sc + w0*(float)r0[i];
  }
  float rinv = 1.f / denom;
  union { u32x4 u; __half2 h[4]; } pk;
#pragma unroll
  for (int i = 0; i < 4; ++i)
    pk.h[i] = __floats2half2_rn(acc[2*i]*rinv, acc[2*i+1]*rinv);
  __builtin_nontemporal_store(pk.u, (u32x4*)(Bh + (long)n*128 + p*8));
}

// ============ BN stats: f16x8 loads, LDS reduce, 2 atomics/thread ============
__global__ void stats_h(const f16x8* __restrict__ X8,
                        float* __restrict__ S, float* __restrict__ Q){
  __shared__ float sb[16][16][8];
  __shared__ float qb[16][16][8];
  int t = threadIdx.x;
  int cg = t & 15, r = t >> 4;
  float s[8] = {0,0,0,0,0,0,0,0}, q[8] = {0,0,0,0,0,0,0,0};
  const int total = N_NODES*16;           // f16x8 units
  for (int idx = blockIdx.x*256 + t; idx < total; idx += gridDim.x*256){
    f16x8 v = X8[idx];
#pragma unroll
    for (int i = 0; i < 8; ++i){
      float f = (float)v[i];
      s[i] += f; q[i] += f*f;
    }
  }
#pragma unroll
  for (int i = 0; i < 8; ++i){ sb[r][cg][i] = s[i]; qb[r][cg][i] = q[i]; }
  __syncthreads();
  if (t < 128){
    int cg2 = t >> 3, j = t & 7;
    float as = 0.f, aq = 0.f;
#pragma unroll
    for (int r2 = 0; r2 < 16; ++r2){ as += sb[r2][cg2][j]; aq += qb[r2][cg2][j]; }
    atomicAdd(&S[cg2*8 + j], as);
    atomicAdd(&Q[cg2*8 + j], aq);
  }
}

// ============ fused pool (BN+ReLU+mean) + MLP head: one block per graph ========
__global__ void poolfinal(const __half* __restrict__ Bh, const int* __restrict__ start,
                          const float* __restrict__ S, const float* __restrict__ Q,
                          const float* __restrict__ gam, const float* __restrict__ bet,
                          const float* __restrict__ fw1, const float* __restrict__ fb1,
                          const float* __restrict__ fw2, const float* __restrict__ fb2,
                          float* __restrict__ out){
  __shared__ float scl[128], shl[128], psum[2][128], p[128], red[2];
  int t = threadIdx.x, gg = blockIdx.x;
  if (t < 128){
    float mean = S[t] * (1.f/(float)N_NODES);
    float var  = fmaxf(Q[t]*(1.f/(float)N_NODES) - mean*mean, 0.f);
    float scale = gam[t]*rsqrtf(var + EPSBN);
    scl[t] = scale;
    shl[t] = bet[t] - mean*scale;
  }
  __syncthreads();
  int s0 = start[gg], s1 = start[gg+1];
  int c = t & 127, h = t >> 7;
  float acc = 0.f;
  for (int n = s0 + h; n < s1; n += 2)
    acc += fmaxf(__half2float(Bh[(long)n*128 + c])*scl[c] + shl[c], 0.f);
  psum[h][c] = acc;
  __syncthreads();
  if (t < 128){
    float cnt = fmaxf((float)(s1 - s0), 1.f);
    p[t] = (psum[0][t] + psum[1][t]) / cnt;
  }
  __syncthreads();
  if (t < 128){
    float a = fb1[t];
    for (int k = 0; k < 128; ++k) a += p[k]*fw1[k*128 + t];
    float z = fmaxf(a, 0.f) * fw2[t];
    for (int off = 32; off; off >>= 1) z += __shfl_down(z, off);
    if ((t & 63) == 0) red[t >> 6] = z;
  }
  __syncthreads();
  if (t == 0) out[gg] = red[0] + red[1] + fb2[0];
}

extern "C" void kernel_launch(void* const* d_in, const int* in_sizes, int n_in,
                              void* d_out, int out_size, void* d_ws, size_t ws_size,
                              hipStream_t stream){
  const float* x    = (const float*)d_in[0];
  const int*   ei   = (const int*)d_in[1];
  const int*   batch= (const int*)d_in[2];
  const float* W1   = (const float*)d_in[3];
  const float* g1   = (const float*)d_in[5];
  const float* be1  = (const float*)d_in[6];
  const float* Wg   = (const float*)d_in[7];
  const float* asr  = (const float*)d_in[8];
  const float* adt  = (const float*)d_in[9];
  const float* g2   = (const float*)d_in[11];
  const float* be2  = (const float*)d_in[12];
  const float* W3   = (const float*)d_in[13];
  const float* g3   = (const float*)d_in[15];
  const float* be3  = (const float*)d_in[16];
  const float* fw1  = (const float*)d_in[17];
  const float* fb1  = (const float*)d_in[18];
  const float* fw2  = (const float*)d_in[19];
  const float* fb2  = (const float*)d_in[20];
  float* out = (float*)d_out;

  const long NH = (long)N_NODES*HDIM;          // 6.4M
  __half* Ah    = (__half*)d_ws;               // [N,H] fp16 (gemm out)
  __half* Bh    = Ah + NH;                     // [N,H] fp16 (agg out)
  __half* Wt1   = Bh + NH;                     // [128,128] fp16 frag-swizzled
  __half* Wtg   = Wt1 + 16384;
  __half* Wt3   = Wtg + 16384;
  float* dis    = (float*)(Wt3 + 16384);       // [N]
  float* al_s   = dis + N_NODES;               // [N]
  float* al_d   = al_s + N_NODES;              // [N]
  int* deg_i    = (int*)(al_d + N_NODES);      // [N]   } zeroed
  float* stats  = (float*)(deg_i + N_NODES);   // [768] } zeroed
  int* gctr     = (int*)(stats + 768);         // [4]   } zeroed
  int* hist     = gctr + 4;                    // [64]  } zeroed
  int2* seg     = (int2*)(hist + 64);          // [N] {e0,cnt}
  int* work     = (int*)(seg + N_NODES);       // [N]
  int* order    = work + N_NODES;              // [N] degree-sorted node ids
  int* colx     = order + N_NODES;             // [E]
  int* start    = colx + N_EDGES;              // [G+1]

  (void)hipMemsetAsync(deg_i, 0, (size_t)(N_NODES + 768 + 4 + 64) * sizeof(int), stream);

  const int TB = 256;
  const int gE  = (N_EDGES + TB - 1)/TB;       // 2344
  const int gMM = (N_NODES + 63)/64;           // 782
  const int gAggG = N_NODES / 16;              // 3125 (1 group per node)

  const _Float16* Ahf = (const _Float16*)Ah;
  const f16x8*    Bh8 = (const f16x8*)Bh;

  // ---- prep (weights + degree + bounds) + CSR build + degree sort ----
  prep_kernel<<<192 + gE + SCAN_B, TB, 0, stream>>>(W1, Wg, W3, Wt1, Wtg, Wt3,
                                                    ei, deg_i, batch, start);
  scan_kernel<<<SCAN_B, TB, 0, stream>>>(deg_i, seg, work, dis, gctr, hist);
  hist_prefix<<<1, 64, 0, stream>>>(hist);
  csr_scatter<<<gE + SCAN_B, TB, 0, stream>>>(ei, work, colx, seg, hist, order);

  // ---- layer 1: GCN ----
  gemm_mfma<false,true,false,true><<<gMM, TB, 0, stream>>>(x, Wt1,
      nullptr, nullptr, nullptr, nullptr, Ah, nullptr, nullptr, nullptr, nullptr, dis);
  gcn_agg<<<gAggG, TB, 0, stream>>>(Ahf, dis, seg, colx, order, Bh);
  stats_h<<<512, TB, 0, stream>>>(Bh8, stats + 0, stats + 128);

  // ---- layer 2: GAT ----
  gemm_mfma<true,false,true,false><<<gMM, TB, 0, stream>>>(Bh, Wtg,
      stats + 0, stats + 128, g1, be1, Ah, asr, adt, al_s, al_d, nullptr);
  gat_agg<<<gAggG, TB, 0, stream>>>(Ahf, al_s, al_d, seg, colx, order, Bh);
  stats_h<<<512, TB, 0, stream>>>(Bh8, stats + 256, stats + 384);

  // ---- layer 3: GCN ----
  gemm_mfma<true,false,false,true><<<gMM, TB, 0, stream>>>(Bh, Wt3,
      stats + 256, stats + 384, g2, be2, Ah, nullptr, nullptr, nullptr, nullptr, dis);
  gcn_agg<<<gAggG, TB, 0, stream>>>(Ahf, dis, seg, colx, order, Bh);
  stats_h<<<512, TB, 0, stream>>>(Bh8, stats + 512, stats + 640);

  // ---- fused pool + MLP head ----
  poolfinal<<<NGRAPH, TB, 0, stream>>>(Bh, start, stats + 512, stats + 640, g3, be3,
                                       fw1, fb1, fw2, fb2, out);
}

// Round 15
// 366.098 us; speedup vs baseline: 1.7600x; 1.7600x over previous
//
#include <hip/hip_runtime.h>
#include <hip/hip_fp16.h>
#include <cstdint>

#define N_NODES 50000
#define N_EDGES 600000
#define HDIM    128
#define NGRAPH  256
#define EPSBN   1e-5f
#define NEG     0.2f
#define SCAN_B  196   // ceil(50000/256)

__device__ __forceinline__ float lrelu(float v){ return v > 0.f ? v : NEG*v; }

typedef _Float16     f16x8 __attribute__((ext_vector_type(8)));
typedef float        f32x4 __attribute__((ext_vector_type(4)));
typedef unsigned int u32x4 __attribute__((ext_vector_type(4)));

// ============ prep: weight swizzle to MFMA-fragment order + degree + bounds ===
__global__ void prep_kernel(const float* __restrict__ W1, const float* __restrict__ Wg,
                            const float* __restrict__ W3, __half* __restrict__ Wt1,
                            __half* __restrict__ Wtg, __half* __restrict__ Wt3,
                            const int* __restrict__ ei, int* __restrict__ degi,
                            const int* __restrict__ batch, int* __restrict__ start){
  int b = blockIdx.x;
  if (b < 192){
    const float* W = (b < 64) ? W1 : (b < 128 ? Wg : W3);
    __half*     Wt = (b < 64) ? Wt1 : (b < 128 ? Wtg : Wt3);
    int idx = (b & 63)*256 + threadIdx.x;     // 0..16383
    int k = idx >> 7, n = idx & 127;
    int kc = k >> 5, q = (k >> 3) & 3, j = k & 7;
    int nt = n >> 4, c16 = n & 15;
    Wt[(((kc*8 + nt)*4 + q)*16 + c16)*8 + j] = __float2half(W[idx]);
  } else if (b < 192 + 2344){
    int e = (b - 192)*256 + threadIdx.x;
    if (e < N_EDGES) atomicAdd(&degi[ei[N_EDGES + e]], 1);
  } else {
    int i = (b - 192 - 2344)*256 + threadIdx.x;
    if (i >= N_NODES) return;
    int bb = batch[i];
    int p = (i == 0) ? -1 : batch[i-1];
    for (int g = p+1; g <= bb; ++g) start[g] = i;
    if (i == N_NODES-1)
      for (int g = bb+1; g <= NGRAPH; ++g) start[g] = N_NODES;
  }
}

// ============ single-kernel CSR offsets: block scan + atomic ticket ============
__global__ void scan_kernel(const int* __restrict__ degi, int2* __restrict__ seg,
                            int* __restrict__ work, float* __restrict__ dis,
                            int* __restrict__ gctr){
  __shared__ int sm[256];
  __shared__ int base;
  int t = threadIdx.x; int i = blockIdx.x*256 + t;
  int v = (i < N_NODES) ? degi[i] : 0;
  if (i < N_NODES) dis[i] = rsqrtf((float)v + 1.f);   // +1 = self loop
  sm[t] = v; __syncthreads();
  for (int off = 1; off < 256; off <<= 1){
    int add = (t >= off) ? sm[t - off] : 0;
    __syncthreads();
    sm[t] += add; __syncthreads();
  }
  if (t == 255) base = atomicAdd(gctr, sm[255]);
  __syncthreads();
  if (i < N_NODES){
    int r = base + sm[t] - v;    // exclusive prefix within block + global base
    seg[i] = make_int2(r, v);
    work[i] = r;
  }
}
__global__ void csr_scatter(const int* __restrict__ ei, int* __restrict__ work,
                            int* __restrict__ colx){
  int e = blockIdx.x*256 + threadIdx.x;
  if (e >= N_EDGES) return;
  int s = ei[e], d = ei[N_EDGES + e];
  int pos = atomicAdd(&work[d], 1);
  colx[pos] = s;
}

// ============ MFMA GEMM: Y = act(X) @ W, fp16 out ============
template<bool BN, bool F32IN, bool ATT, bool SCALE>
__global__ __launch_bounds__(256) void gemm_mfma(const void* __restrict__ Xv,
    const __half* __restrict__ Wt,
    const float* __restrict__ S, const float* __restrict__ Q,
    const float* __restrict__ gam, const float* __restrict__ bet,
    __half* __restrict__ Yh,
    const float* __restrict__ asr, const float* __restrict__ adt,
    float* __restrict__ al_s, float* __restrict__ al_d,
    const float* __restrict__ dis){
  __shared__ _Float16 scl[128], shl[128];
  const int t    = threadIdx.x;
  if (BN){
    if (t < 128){
      float mean = S[t] * (1.f/(float)N_NODES);
      float var  = fmaxf(Q[t]*(1.f/(float)N_NODES) - mean*mean, 0.f);
      float scale = gam[t]*rsqrtf(var + EPSBN);
      float shift = bet[t] - mean*scale;
      scl[t] = (_Float16)scale;
      shl[t] = (_Float16)shift;
    }
    __syncthreads();
  }
  const int wave = t >> 6, lane = t & 63;
  const int q    = lane >> 4, c16 = lane & 15;
  const int m0   = blockIdx.x*64 + wave*16;
  const int row  = m0 + c16;
  const int arow = (row > N_NODES-1) ? N_NODES-1 : row;   // tail clamp (reads only)

  f32x4 acc[8];
#pragma unroll
  for (int i = 0; i < 8; ++i) acc[i] = (f32x4){0.f,0.f,0.f,0.f};

  const f16x8* Wt8 = (const f16x8*)Wt;

#pragma unroll
  for (int kc = 0; kc < 4; ++kc){
    const int kof = kc*32 + q*8;
    f16x8 a;
    if (F32IN){
      const float* xp = (const float*)Xv + (long)arow*128 + kof;
      float4 x0 = *(const float4*)xp;
      float4 x1 = *(const float4*)(xp + 4);
      a[0]=(_Float16)x0.x; a[1]=(_Float16)x0.y; a[2]=(_Float16)x0.z; a[3]=(_Float16)x0.w;
      a[4]=(_Float16)x1.x; a[5]=(_Float16)x1.y; a[6]=(_Float16)x1.z; a[7]=(_Float16)x1.w;
    } else {
      f16x8 raw = *(const f16x8*)((const _Float16*)Xv + (long)arow*128 + kof);
      if (BN){
        f16x8 scv = *(const f16x8*)(scl + kof);
        f16x8 shv = *(const f16x8*)(shl + kof);
#pragma unroll
        for (int i = 0; i < 8; ++i){
          _Float16 v = (_Float16)(raw[i]*scv[i] + shv[i]);
          a[i] = v > (_Float16)0 ? v : (_Float16)0;
        }
      } else {
        a = raw;
      }
    }
#pragma unroll
    for (int nt = 0; nt < 8; ++nt){
      f16x8 b = Wt8[(kc*8 + nt)*64 + lane];   // lane-contiguous fragment
      acc[nt] = __builtin_amdgcn_mfma_f32_16x16x32_f16(b, a, acc[nt], 0, 0, 0);
    }
  }
  float rs = SCALE ? dis[arow] : 1.f;
  if (row < N_NODES){
    __half* yp = Yh + (long)row*128 + q*4;
#pragma unroll
    for (int nt = 0; nt < 8; ++nt){
      union { uint2 u; __half2 h[2]; } pk;
      pk.h[0] = __floats2half2_rn(acc[nt][0]*rs, acc[nt][1]*rs);
      pk.h[1] = __floats2half2_rn(acc[nt][2]*rs, acc[nt][3]*rs);
      *(uint2*)(yp + nt*16) = pk.u;
    }
  }
  if (ATT){
    float s = 0.f, d = 0.f;
#pragma unroll
    for (int nt = 0; nt < 8; ++nt){
      float4 av = *(const float4*)(asr + nt*16 + q*4);
      float4 bv = *(const float4*)(adt + nt*16 + q*4);
      s += acc[nt][0]*av.x + acc[nt][1]*av.y + acc[nt][2]*av.z + acc[nt][3]*av.w;
      d += acc[nt][0]*bv.x + acc[nt][1]*bv.y + acc[nt][2]*bv.z + acc[nt][3]*bv.w;
    }
    s += __shfl_xor(s, 16); s += __shfl_xor(s, 32);
    d += __shfl_xor(d, 16); d += __shfl_xor(d, 32);
    if (q == 0 && row < N_NODES){ al_s[row] = s; al_d[row] = d; }
  }
}

// ============ GCN aggregation: 1 group (16 lanes) = 1 node, zero shuffles ======
__global__ __launch_bounds__(256) void gcn_agg(const _Float16* __restrict__ Ah,
    const float* __restrict__ dis, const int2* __restrict__ seg,
    const int* __restrict__ colx, __half* __restrict__ Bh){
  const int t = threadIdx.x;
  const int grp = t >> 4, p = t & 15;
  const int n = blockIdx.x*16 + grp;          // 3125*16 = 50000 exact
  const int2 sg = seg[n];
  const int e0 = sg.x, cnt = sg.y;
  f16x8 self = *(const f16x8*)(Ah + (long)n*128 + p*8);
  float acc[8];
#pragma unroll
  for (int i = 0; i < 8; ++i) acc[i] = (float)self[i];
  int j = 0;
  for (; j + 1 < cnt; j += 2){
    int s0 = colx[e0 + j];
    int s1 = colx[e0 + j + 1];
    f16x8 r0 = *(const f16x8*)(Ah + (long)s0*128 + p*8);
    f16x8 r1 = *(const f16x8*)(Ah + (long)s1*128 + p*8);
#pragma unroll
    for (int i = 0; i < 8; ++i) acc[i] += (float)r0[i] + (float)r1[i];
  }
  if (j < cnt){
    int s0 = colx[e0 + j];
    f16x8 r0 = *(const f16x8*)(Ah + (long)s0*128 + p*8);
#pragma unroll
    for (int i = 0; i < 8; ++i) acc[i] += (float)r0[i];
  }
  float dn = dis[n];
  union { u32x4 u; __half2 h[4]; } pk;
#pragma unroll
  for (int i = 0; i < 4; ++i)
    pk.h[i] = __floats2half2_rn(acc[2*i]*dn, acc[2*i+1]*dn);
  __builtin_nontemporal_store(pk.u, (u32x4*)(Bh + (long)n*128 + p*8));
}

// ============ GAT aggregation: 1 group = 1 node, ONLINE softmax (single pass) ==
__global__ __launch_bounds__(256) void gat_agg(const _Float16* __restrict__ Ah,
    const float* __restrict__ al_s, const float* __restrict__ al_d,
    const int2* __restrict__ seg, const int* __restrict__ colx,
    __half* __restrict__ Bh){
  const int t = threadIdx.x;
  const int grp = t >> 4, p = t & 15;
  const int n = blockIdx.x*16 + grp;
  const int2 sg = seg[n];
  const int e0 = sg.x, cnt = sg.y;
  const float adn = al_d[n];
  float m = lrelu(al_s[n] + adn);     // self seeds the running max
  float denom = 1.f;                  // self weight exp(0)
  f16x8 self = *(const f16x8*)(Ah + (long)n*128 + p*8);
  float acc[8];
#pragma unroll
  for (int i = 0; i < 8; ++i) acc[i] = (float)self[i];
  int j = 0;
  for (; j + 1 < cnt; j += 2){
    int s0 = colx[e0 + j];
    int s1 = colx[e0 + j + 1];
    float a0 = lrelu(al_s[s0] + adn);
    float a1 = lrelu(al_s[s1] + adn);
    f16x8 r0 = *(const f16x8*)(Ah + (long)s0*128 + p*8);
    f16x8 r1 = *(const f16x8*)(Ah + (long)s1*128 + p*8);
    float nm = fmaxf(m, fmaxf(a0, a1));
    float sc = __expf(m - nm);
    float w0 = __expf(a0 - nm);
    float w1 = __expf(a1 - nm);
    denom = denom*sc + w0 + w1;
    m = nm;
#pragma unroll
    for (int i = 0; i < 8; ++i)
      acc[i] = acc[i]*sc + w0*(float)r0[i] + w1*(float)r1[i];
  }
  if (j < cnt){
    int s0 = colx[e0 + j];
    float a0 = lrelu(al_s[s0] + adn);
    f16x8 r0 = *(const f16x8*)(Ah + (long)s0*128 + p*8);
    float nm = fmaxf(m, a0);
    float sc = __expf(m - nm);
    float w0 = __expf(a0 - nm);
    denom = denom*sc + w0;
#pragma unroll
    for (int i = 0; i < 8; ++i) acc[i] = acc[i]*sc + w0*(float)r0[i];
  }
  float rinv = 1.f / denom;
  union { u32x4 u; __half2 h[4]; } pk;
#pragma unroll
  for (int i = 0; i < 4; ++i)
    pk.h[i] = __floats2half2_rn(acc[2*i]*rinv, acc[2*i+1]*rinv);
  __builtin_nontemporal_store(pk.u, (u32x4*)(Bh + (long)n*128 + p*8));
}

// ============ BN stats: f16x8 loads, LDS reduce, 2 atomics/thread ============
__global__ void stats_h(const f16x8* __restrict__ X8,
                        float* __restrict__ S, float* __restrict__ Q){
  __shared__ float sb[16][16][8];
  __shared__ float qb[16][16][8];
  int t = threadIdx.x;
  int cg = t & 15, r = t >> 4;
  float s[8] = {0,0,0,0,0,0,0,0}, q[8] = {0,0,0,0,0,0,0,0};
  const int total = N_NODES*16;           // f16x8 units
  for (int idx = blockIdx.x*256 + t; idx < total; idx += gridDim.x*256){
    f16x8 v = X8[idx];
#pragma unroll
    for (int i = 0; i < 8; ++i){
      float f = (float)v[i];
      s[i] += f; q[i] += f*f;
    }
  }
#pragma unroll
  for (int i = 0; i < 8; ++i){ sb[r][cg][i] = s[i]; qb[r][cg][i] = q[i]; }
  __syncthreads();
  if (t < 128){
    int cg2 = t >> 3, j = t & 7;
    float as = 0.f, aq = 0.f;
#pragma unroll
    for (int r2 = 0; r2 < 16; ++r2){ as += sb[r2][cg2][j]; aq += qb[r2][cg2][j]; }
    atomicAdd(&S[cg2*8 + j], as);
    atomicAdd(&Q[cg2*8 + j], aq);
  }
}

// ============ fused pool (BN+ReLU+mean) + MLP head: one block per graph ========
__global__ void poolfinal(const __half* __restrict__ Bh, const int* __restrict__ start,
                          const float* __restrict__ S, const float* __restrict__ Q,
                          const float* __restrict__ gam, const float* __restrict__ bet,
                          const float* __restrict__ fw1, const float* __restrict__ fb1,
                          const float* __restrict__ fw2, const float* __restrict__ fb2,
                          float* __restrict__ out){
  __shared__ float scl[128], shl[128], psum[2][128], p[128], red[2];
  int t = threadIdx.x, gg = blockIdx.x;
  if (t < 128){
    float mean = S[t] * (1.f/(float)N_NODES);
    float var  = fmaxf(Q[t]*(1.f/(float)N_NODES) - mean*mean, 0.f);
    float scale = gam[t]*rsqrtf(var + EPSBN);
    scl[t] = scale;
    shl[t] = bet[t] - mean*scale;
  }
  __syncthreads();
  int s0 = start[gg], s1 = start[gg+1];
  int c = t & 127, h = t >> 7;
  float acc = 0.f;
  for (int n = s0 + h; n < s1; n += 2)
    acc += fmaxf(__half2float(Bh[(long)n*128 + c])*scl[c] + shl[c], 0.f);
  psum[h][c] = acc;
  __syncthreads();
  if (t < 128){
    float cnt = fmaxf((float)(s1 - s0), 1.f);
    p[t] = (psum[0][t] + psum[1][t]) / cnt;
  }
  __syncthreads();
  if (t < 128){
    float a = fb1[t];
    for (int k = 0; k < 128; ++k) a += p[k]*fw1[k*128 + t];
    float z = fmaxf(a, 0.f) * fw2[t];
    for (int off = 32; off; off >>= 1) z += __shfl_down(z, off);
    if ((t & 63) == 0) red[t >> 6] = z;
  }
  __syncthreads();
  if (t == 0) out[gg] = red[0] + red[1] + fb2[0];
}

extern "C" void kernel_launch(void* const* d_in, const int* in_sizes, int n_in,
                              void* d_out, int out_size, void* d_ws, size_t ws_size,
                              hipStream_t stream){
  const float* x    = (const float*)d_in[0];
  const int*   ei   = (const int*)d_in[1];
  const int*   batch= (const int*)d_in[2];
  const float* W1   = (const float*)d_in[3];
  const float* g1   = (const float*)d_in[5];
  const float* be1  = (const float*)d_in[6];
  const float* Wg   = (const float*)d_in[7];
  const float* asr  = (const float*)d_in[8];
  const float* adt  = (const float*)d_in[9];
  const float* g2   = (const float*)d_in[11];
  const float* be2  = (const float*)d_in[12];
  const float* W3   = (const float*)d_in[13];
  const float* g3   = (const float*)d_in[15];
  const float* be3  = (const float*)d_in[16];
  const float* fw1  = (const float*)d_in[17];
  const float* fb1  = (const float*)d_in[18];
  const float* fw2  = (const float*)d_in[19];
  const float* fb2  = (const float*)d_in[20];
  float* out = (float*)d_out;

  const long NH = (long)N_NODES*HDIM;          // 6.4M
  __half* Ah    = (__half*)d_ws;               // [N,H] fp16 (gemm out)
  __half* Bh    = Ah + NH;                     // [N,H] fp16 (agg out)
  __half* Wt1   = Bh + NH;                     // [128,128] fp16 frag-swizzled
  __half* Wtg   = Wt1 + 16384;
  __half* Wt3   = Wtg + 16384;
  float* dis    = (float*)(Wt3 + 16384);       // [N]
  float* al_s   = dis + N_NODES;               // [N]
  float* al_d   = al_s + N_NODES;              // [N]
  int* deg_i    = (int*)(al_d + N_NODES);      // [N]   } zeroed
  float* stats  = (float*)(deg_i + N_NODES);   // [768] } zeroed
  int* gctr     = (int*)(stats + 768);         // [4]   } zeroed
  int2* seg     = (int2*)(gctr + 4);           // [N] {e0,cnt}
  int* work     = (int*)(seg + N_NODES);       // [N]
  int* colx     = work + N_NODES;              // [E]
  int* start    = colx + N_EDGES;              // [G+1]

  (void)hipMemsetAsync(deg_i, 0, (size_t)(N_NODES + 768 + 4) * sizeof(int), stream);

  const int TB = 256;
  const int gE  = (N_EDGES + TB - 1)/TB;       // 2344
  const int gMM = (N_NODES + 63)/64;           // 782
  const int gAggG = N_NODES / 16;              // 3125 (1 group per node)

  const _Float16* Ahf = (const _Float16*)Ah;
  const f16x8*    Bh8 = (const f16x8*)Bh;

  // ---- prep (weights + degree + bounds) + CSR build ----
  prep_kernel<<<192 + gE + SCAN_B, TB, 0, stream>>>(W1, Wg, W3, Wt1, Wtg, Wt3,
                                                    ei, deg_i, batch, start);
  scan_kernel<<<SCAN_B, TB, 0, stream>>>(deg_i, seg, work, dis, gctr);
  csr_scatter<<<gE, TB, 0, stream>>>(ei, work, colx);

  // ---- layer 1: GCN ----
  gemm_mfma<false,true,false,true><<<gMM, TB, 0, stream>>>(x, Wt1,
      nullptr, nullptr, nullptr, nullptr, Ah, nullptr, nullptr, nullptr, nullptr, dis);
  gcn_agg<<<gAggG, TB, 0, stream>>>(Ahf, dis, seg, colx, Bh);
  stats_h<<<512, TB, 0, stream>>>(Bh8, stats + 0, stats + 128);

  // ---- layer 2: GAT ----
  gemm_mfma<true,false,true,false><<<gMM, TB, 0, stream>>>(Bh, Wtg,
      stats + 0, stats + 128, g1, be1, Ah, asr, adt, al_s, al_d, nullptr);
  gat_agg<<<gAggG, TB, 0, stream>>>(Ahf, al_s, al_d, seg, colx, Bh);
  stats_h<<<512, TB, 0, stream>>>(Bh8, stats + 256, stats + 384);

  // ---- layer 3: GCN ----
  gemm_mfma<true,false,false,true><<<gMM, TB, 0, stream>>>(Bh, Wt3,
      stats + 256, stats + 384, g2, be2, Ah, nullptr, nullptr, nullptr, nullptr, dis);
  gcn_agg<<<gAggG, TB, 0, stream>>>(Ahf, dis, seg, colx, Bh);
  stats_h<<<512, TB, 0, stream>>>(Bh8, stats + 512, stats + 640);

  // ---- fused pool + MLP head ----
  poolfinal<<<NGRAPH, TB, 0, stream>>>(Bh, start, stats + 512, stats + 640, g3, be3,
                                       fw1, fb1, fw2, fb2, out);
}